// Round 4
// baseline (395.297 us; speedup 1.0000x reference)
//
#include <hip/hip_runtime.h>
#include <stdint.h>

#define BB 128
#define WW 512
#define HH 512
#define TILE 128
#define BK 64

typedef __attribute__((ext_vector_type(8))) short bf16x8;
typedef __attribute__((ext_vector_type(4))) float f32x4;

__device__ __forceinline__ float bf2f(unsigned short u) {
  union { unsigned int i; float f; } v;
  v.i = ((unsigned int)u) << 16;
  return v.f;
}
// pack two f32 into two bf16 (bit-truncation; |rel err| <= 2^-8, fine vs 6.1e-2 thr)
__device__ __forceinline__ unsigned int pack_bf2(float lo, float hi) {
  union { float f; unsigned int u; } a, b;
  a.f = lo; b.f = hi;
  return (a.u >> 16) | (b.u & 0xFFFF0000u);
}
__device__ __forceinline__ float dot4v(float4 u, float4 v) {
  return u.x * v.x + u.y * v.y + u.z * v.z + u.w * v.w;
}
__device__ __forceinline__ void gload_lds16(const void* src, void* lds_dst) {
  __builtin_amdgcn_global_load_lds(
      (const __attribute__((address_space(1))) unsigned int*)src,
      (__attribute__((address_space(3))) unsigned int*)lds_dst, 16, 0, 0);
}

// ============ K0: wide prep kernel ============
// blocks 0..11   : [gw | gfo] = g @ [w_w ; W_w].T  (MFMA GEMM, verified)
// blocks 12..75  : u_w -> pre-swizzled bf16 image u_wb (16 tiles of 256x64)
// primary mode, blocks 76..587: h -> pre-swizzled bf16 image hb (per (b,wc):
//     8 kt-tiles of 128x64, row-swizzled e^((row&7)<<3)) + column sums -> hsumP
// fallback mode, blocks 76..203: column sums of h only (f32) -> hsumP partial 0
__global__ __launch_bounds__(256) void k0(
    const float* __restrict__ g, const float* __restrict__ W_w,
    const float* __restrict__ w_w, const float* __restrict__ u_w,
    const float* __restrict__ h,
    float* __restrict__ gw, float* __restrict__ gfo,
    unsigned short* __restrict__ u_wb, unsigned short* __restrict__ hb,
    float* __restrict__ hsumP, int primary) {
  __shared__ __align__(16) unsigned short As[TILE * BK];
  __shared__ __align__(16) unsigned short Bs[TILE * BK];
  __shared__ float colred[4][64];
  const int bid = blockIdx.x;
  const int t = threadIdx.x;

  if (bid >= 76) {
    if (primary) {
      // ---- h convert + colsum: id = b*4+wc, tile = 128 rows x 512 cols
      const int id = bid - 76;                      // 0..511
      const float* hsrc = h + (size_t)id * TILE * HH;
      unsigned short* hdst = hb + (size_t)id * (8 * 8192);
      const int row = t >> 1;                       // 0..127
      const int cpart = (t & 1) * 32;               // 0 or 32
      const int sw = (row & 7) << 3;
      for (int kt = 0; kt < 8; ++kt) {
        const float4* sp = (const float4*)(hsrc + (size_t)row * HH + kt * 64 + cpart);
        float4 v[8];
#pragma unroll
        for (int q = 0; q < 8; ++q) v[q] = sp[q];
#pragma unroll
        for (int eg = 0; eg < 4; ++eg) {
          uint4 pv;
          pv.x = pack_bf2(v[2 * eg].x, v[2 * eg].y);
          pv.y = pack_bf2(v[2 * eg].z, v[2 * eg].w);
          pv.z = pack_bf2(v[2 * eg + 1].x, v[2 * eg + 1].y);
          pv.w = pack_bf2(v[2 * eg + 1].z, v[2 * eg + 1].w);
          const int off = row * 64 + ((cpart + eg * 8) ^ sw);
          *(uint4*)(As + off) = pv;
          *(uint4*)(hdst + (size_t)kt * 8192 + off) = pv;
        }
        __syncthreads();
        {
          const int col = t & 63, gq = t >> 6;
          float s = 0.f;
#pragma unroll
          for (int rr = 0; rr < 32; ++rr) {
            const int rw = gq * 32 + rr;
            s += bf2f(As[rw * 64 + (col ^ ((rw & 7) << 3))]);
          }
          colred[gq][col] = s;
        }
        __syncthreads();
        if (t < 64)
          hsumP[(size_t)id * HH + kt * 64 + t] =
              colred[0][t] + colred[1][t] + colred[2][t] + colred[3][t];
        __syncthreads();
      }
    } else {
      // ---- fallback: colsum only, id = b (0..127); partials 1..3 zeroed
      const int b = bid - 76;
      const float* hp = h + (size_t)b * WW * HH;
      const int col0 = t * 2;
      float s0 = 0.f, s1 = 0.f;
      for (int w = 0; w < WW; ++w) {
        const float2 v = *(const float2*)(hp + (size_t)w * HH + col0);
        s0 += v.x; s1 += v.y;
      }
      hsumP[(size_t)b * 4 * HH + col0] = s0;
      hsumP[(size_t)b * 4 * HH + col0 + 1] = s1;
#pragma unroll
      for (int p = 1; p < 4; ++p) {
        hsumP[((size_t)b * 4 + p) * HH + col0] = 0.f;
        hsumP[((size_t)b * 4 + p) * HH + col0 + 1] = 0.f;
      }
    }
    return;
  }

  if (bid >= 12) {
    // ---- u_w convert: 32768 16B-chunks, 2 per thread over 64 blocks
    const int cid0 = (bid - 12) * 256 + t;
    for (int idx = cid0; idx < 32768; idx += 16384) {
      const int tile = idx >> 11;        // 2048 chunks per 32KB tile
      const int rem  = idx & 2047;
      const int row  = rem >> 3;         // 0..255
      const int eg   = (rem & 7) * 8;    // 0,8,..,56
      const int nh   = tile >> 3;
      const int kt   = tile & 7;
      const int c0   = kt * 64 + (eg ^ ((row & 7) << 3));
      const float4* sp = (const float4*)(u_w + (size_t)(nh * 256 + row) * HH + c0);
      float4 s0 = sp[0], s1 = sp[1];
      uint4 pv;
      pv.x = pack_bf2(s0.x, s0.y); pv.y = pack_bf2(s0.z, s0.w);
      pv.z = pack_bf2(s1.x, s1.y); pv.w = pack_bf2(s1.z, s1.w);
      *(uint4*)(u_wb + (size_t)idx * 8) = pv;
    }
    return;
  }

  // ---- k1 MFMA GEMM (verified)
  const int nc = bid;
  const int lane = t & 63, wave = t >> 6;
  const int wm = wave >> 1, wn = wave & 1;
  const int l15 = lane & 15, quad = lane >> 4;

  const float* wsrc = (nc < 4) ? (w_w + (size_t)nc * TILE * HH)
                               : (W_w + (size_t)(nc - 4) * TILE * HH);

  const f32x4 zero = {0.f, 0.f, 0.f, 0.f};
  f32x4 acc[4][4];
#pragma unroll
  for (int i = 0; i < 4; ++i)
#pragma unroll
    for (int j = 0; j < 4; ++j) acc[i][j] = zero;

  const int srow = t >> 3;
  const int scol = (t & 7) * 8;

  for (int kt = 0; kt < 8; ++kt) {
    const int k0i = kt * BK;
#pragma unroll
    for (int p = 0; p < 4; ++p) {
      const int row = p * 32 + srow;
      const float4* ap = (const float4*)(g    + (size_t)row * HH + k0i + scol);
      const float4* bp = (const float4*)(wsrc + (size_t)row * HH + k0i + scol);
      float4 a0 = ap[0], a1 = ap[1], b0 = bp[0], b1 = bp[1];
      uint4 av, bv;
      av.x = pack_bf2(a0.x, a0.y); av.y = pack_bf2(a0.z, a0.w);
      av.z = pack_bf2(a1.x, a1.y); av.w = pack_bf2(a1.z, a1.w);
      bv.x = pack_bf2(b0.x, b0.y); bv.y = pack_bf2(b0.z, b0.w);
      bv.z = pack_bf2(b1.x, b1.y); bv.w = pack_bf2(b1.z, b1.w);
      *(uint4*)(As + row * BK + scol) = av;
      *(uint4*)(Bs + row * BK + scol) = bv;
    }
    __syncthreads();
#pragma unroll
    for (int ks = 0; ks < 2; ++ks) {
      bf16x8 af[4], bg[4];
#pragma unroll
      for (int i = 0; i < 4; ++i)
        af[i] = *(const bf16x8*)(As + (wm * 64 + i * 16 + l15) * BK + ks * 32 + quad * 8);
#pragma unroll
      for (int j = 0; j < 4; ++j)
        bg[j] = *(const bf16x8*)(Bs + (wn * 64 + j * 16 + l15) * BK + ks * 32 + quad * 8);
#pragma unroll
      for (int i = 0; i < 4; ++i)
#pragma unroll
        for (int j = 0; j < 4; ++j)
          acc[i][j] = __builtin_amdgcn_mfma_f32_16x16x32_bf16(af[i], bg[j], acc[i][j], 0, 0, 0);
    }
    __syncthreads();
  }

#pragma unroll
  for (int j = 0; j < 4; ++j) {
    const int nl = wn * 64 + j * 16 + l15;
#pragma unroll
    for (int i = 0; i < 4; ++i) {
#pragma unroll
      for (int r = 0; r < 4; ++r) {
        const int b = wm * 64 + i * 16 + quad * 4 + r;
        const float v = acc[i][j][r];
        if (nc < 4) gw[(size_t)b * HH + nc * TILE + nl] = v;
        else        gfo[(size_t)b * 2 * HH + (nc - 4) * TILE + nl] = v;
      }
    }
  }
}

// ============ K2 primary: pure gload_lds GEMM + fused epilogue ============
// grid 1024 = (b, wc, nh). Block 128x256, 512 thr (8 waves 2Mx4N, 64x64 tiles).
// A from hb image, B from u_wb image — both pre-swizzled, loop has ~zero VALU.
__global__ __launch_bounds__(512, 4) void k2p(
    const unsigned short* __restrict__ hb, const float* __restrict__ c,
    const unsigned short* __restrict__ u_wb, const float* __restrict__ u_b,
    const float* __restrict__ gw,
    float* __restrict__ denP, float* __restrict__ numP) {
  __shared__ __align__(16) unsigned short Bs[256 * 64];   // 32 KB
  __shared__ __align__(16) unsigned short As[128 * 64];   // 16 KB
  // epilogue red-buffers aliased over As (free after final barrier)
  float (*redD)[256] = (float (*)[256])(void*)As;
  float (*redN)[256] = (float (*)[256])(void*)(As + 1024);

  const int bid = blockIdx.x;
  const int b  = bid >> 3;
  const int wc = (bid >> 1) & 3;
  const int nh = bid & 1;
  const int t = threadIdx.x;
  const int lane = t & 63, wave = t >> 6;
  const int wm = wave >> 2, wn = wave & 3;
  const int l15 = lane & 15, quad = lane >> 4;

  const size_t hbase = ((size_t)b * WW + (size_t)wc * 128) * HH;
  const unsigned short* hbA = hb + (size_t)(bid >> 1) * (8 * 8192);
  const unsigned short* ubase = u_wb + (size_t)nh * 8 * 16384;

  const f32x4 zero = {0.f, 0.f, 0.f, 0.f};
  f32x4 acc[4][4];
#pragma unroll
  for (int i = 0; i < 4; ++i)
#pragma unroll
    for (int j = 0; j < 4; ++j) acc[i][j] = zero;

  for (int kt = 0; kt < 8; ++kt) {
    // A: 16 KB = 16 segs of 1 KB; wave handles segs wave*2, wave*2+1
#pragma unroll
    for (int it = 0; it < 2; ++it) {
      const int s = wave * 2 + it;
      gload_lds16(hbA + (size_t)kt * 8192 + (size_t)s * 512 + (size_t)lane * 8,
                  As + (size_t)s * 512);
    }
    // B: 32 KB = 32 segs; wave handles segs wave*4 .. +3
#pragma unroll
    for (int it = 0; it < 4; ++it) {
      const int s = wave * 4 + it;
      gload_lds16(ubase + (size_t)kt * 16384 + (size_t)s * 512 + (size_t)lane * 8,
                  Bs + (size_t)s * 512);
    }
    __syncthreads();

#pragma unroll
    for (int ks = 0; ks < 2; ++ks) {
      bf16x8 af[4], bg[4];
#pragma unroll
      for (int i = 0; i < 4; ++i) {
        const int row = wm * 64 + i * 16 + l15;
        af[i] = *(const bf16x8*)(As + row * 64 + ((ks * 32 + quad * 8) ^ ((row & 7) << 3)));
      }
#pragma unroll
      for (int j = 0; j < 4; ++j) {
        const int row = wn * 64 + j * 16 + l15;
        bg[j] = *(const bf16x8*)(Bs + row * 64 + ((ks * 32 + quad * 8) ^ ((row & 7) << 3)));
      }
#pragma unroll
      for (int i = 0; i < 4; ++i)
#pragma unroll
        for (int j = 0; j < 4; ++j)
          acc[i][j] = __builtin_amdgcn_mfma_f32_16x16x32_bf16(af[i], bg[j], acc[i][j], 0, 0, 0);
    }
    __syncthreads();
  }

  // Epilogue: e = exp(sigmoid(Z + gw + u_b)); reduce over this block's 128 w's.
  const int N0 = nh * 256;
#pragma unroll
  for (int j = 0; j < 4; ++j) {
    const int n = wn * 64 + j * 16 + l15;
    const float gwub = gw[(size_t)b * HH + N0 + n] + u_b[N0 + n];
    float dsum = 0.f, nsum = 0.f;
#pragma unroll
    for (int i = 0; i < 4; ++i) {
#pragma unroll
      for (int r = 0; r < 4; ++r) {
        const int m = wm * 64 + i * 16 + quad * 4 + r;
        const float z = acc[i][j][r] + gwub;
        const float sig = 1.f / (1.f + __expf(-z));
        const float e = __expf(sig);
        dsum += e;
        nsum += e * c[hbase + (size_t)m * HH + N0 + n];
      }
    }
    dsum += __shfl_xor(dsum, 16);
    dsum += __shfl_xor(dsum, 32);
    nsum += __shfl_xor(nsum, 16);
    nsum += __shfl_xor(nsum, 32);
    if (quad == 0) { redD[wm][n] = dsum; redN[wm][n] = nsum; }
  }
  __syncthreads();
  if (t < 256) {
    const size_t o = ((size_t)b * 4 + wc) * HH + N0 + t;
    denP[o] = redD[0][t] + redD[1][t];
    numP[o] = redN[0][t] + redN[1][t];
  }
}

// ============ K2 fallback: round-2 structure (f32 h staging), no colsum ============
__global__ __launch_bounds__(512, 4) void k2f(
    const float* __restrict__ h, const float* __restrict__ c,
    const unsigned short* __restrict__ u_wb, const float* __restrict__ u_b,
    const float* __restrict__ gw,
    float* __restrict__ denP, float* __restrict__ numP) {
  __shared__ __align__(16) unsigned short Bs[256 * 64];
  __shared__ __align__(16) unsigned short As[128 * 64];
  float (*redD)[256] = (float (*)[256])(void*)As;
  float (*redN)[256] = (float (*)[256])(void*)(As + 1024);

  const int bid = blockIdx.x;
  const int b  = bid >> 3;
  const int wc = (bid >> 1) & 3;
  const int nh = bid & 1;
  const int t = threadIdx.x;
  const int lane = t & 63, wave = t >> 6;
  const int wm = wave >> 2, wn = wave & 3;
  const int l15 = lane & 15, quad = lane >> 4;

  const size_t hbase = ((size_t)b * WW + (size_t)wc * 128) * HH;
  const unsigned short* ubase = u_wb + (size_t)nh * 8 * 16384;

  const f32x4 zero = {0.f, 0.f, 0.f, 0.f};
  f32x4 acc[4][4];
#pragma unroll
  for (int i = 0; i < 4; ++i)
#pragma unroll
    for (int j = 0; j < 4; ++j) acc[i][j] = zero;

  const int srow = t >> 3;
  const int scol = (t & 7) * 8;

  for (int kt = 0; kt < 8; ++kt) {
    const int k0i = kt * 64;
#pragma unroll
    for (int it = 0; it < 4; ++it) {
      const int s = wave * 4 + it;
      gload_lds16(ubase + ((size_t)kt * 16384 + (size_t)s * 512 + (size_t)lane * 8),
                  Bs + (size_t)s * 512);
    }
#pragma unroll
    for (int p = 0; p < 2; ++p) {
      const int row = p * 64 + srow;
      const float4* ap = (const float4*)(h + hbase + (size_t)row * HH + k0i + scol);
      float4 a0 = ap[0], a1 = ap[1];
      uint4 av;
      av.x = pack_bf2(a0.x, a0.y); av.y = pack_bf2(a0.z, a0.w);
      av.z = pack_bf2(a1.x, a1.y); av.w = pack_bf2(a1.z, a1.w);
      *(uint4*)(As + row * 64 + (scol ^ ((row & 7) << 3))) = av;
    }
    __syncthreads();
#pragma unroll
    for (int ks = 0; ks < 2; ++ks) {
      bf16x8 af[4], bg[4];
#pragma unroll
      for (int i = 0; i < 4; ++i) {
        const int row = wm * 64 + i * 16 + l15;
        af[i] = *(const bf16x8*)(As + row * 64 + ((ks * 32 + quad * 8) ^ ((row & 7) << 3)));
      }
#pragma unroll
      for (int j = 0; j < 4; ++j) {
        const int row = wn * 64 + j * 16 + l15;
        bg[j] = *(const bf16x8*)(Bs + row * 64 + ((ks * 32 + quad * 8) ^ ((row & 7) << 3)));
      }
#pragma unroll
      for (int i = 0; i < 4; ++i)
#pragma unroll
        for (int j = 0; j < 4; ++j)
          acc[i][j] = __builtin_amdgcn_mfma_f32_16x16x32_bf16(af[i], bg[j], acc[i][j], 0, 0, 0);
    }
    __syncthreads();
  }

  const int N0 = nh * 256;
#pragma unroll
  for (int j = 0; j < 4; ++j) {
    const int n = wn * 64 + j * 16 + l15;
    const float gwub = gw[(size_t)b * HH + N0 + n] + u_b[N0 + n];
    float dsum = 0.f, nsum = 0.f;
#pragma unroll
    for (int i = 0; i < 4; ++i) {
#pragma unroll
      for (int r = 0; r < 4; ++r) {
        const int m = wm * 64 + i * 16 + quad * 4 + r;
        const float z = acc[i][j][r] + gwub;
        const float sig = 1.f / (1.f + __expf(-z));
        const float e = __expf(sig);
        dsum += e;
        nsum += e * c[hbase + (size_t)m * HH + N0 + n];
      }
    }
    dsum += __shfl_xor(dsum, 16);
    dsum += __shfl_xor(dsum, 32);
    nsum += __shfl_xor(nsum, 16);
    nsum += __shfl_xor(nsum, 32);
    if (quad == 0) { redD[wm][n] = dsum; redN[wm][n] = nsum; }
  }
  __syncthreads();
  if (t < 256) {
    const size_t o = ((size_t)b * 4 + wc) * HH + N0 + t;
    denP[o] = redD[0][t] + redD[1][t];
    numP[o] = redN[0][t] + redN[1][t];
  }
}

// -------- K3: fo gates + final outputs. grid 512 = (b, q); 256 thr = 4 waves.
__global__ __launch_bounds__(256) void k3_final(
    const float* __restrict__ c_g, const float* __restrict__ U_w,
    const float* __restrict__ U_b,
    const float* __restrict__ gfo, const float* __restrict__ hsumP,
    const float* __restrict__ denP, const float* __restrict__ numP,
    float* __restrict__ out) {
  __shared__ float logitL[256];
  __shared__ float ncL[128];
  __shared__ float oL[128];
  const int bid = blockIdx.x;
  const int b = bid >> 2, q = bid & 3;
  const int t = threadIdx.x;
  const int lane = t & 63, wave = t >> 6;

  // ha in registers: lane l holds k = 8l .. 8l+7
  float4 ha0 = {0.f, 0.f, 0.f, 0.f}, ha1 = {0.f, 0.f, 0.f, 0.f};
  {
    const float4* hp = (const float4*)(hsumP + (size_t)b * 4 * HH);
#pragma unroll
    for (int p = 0; p < 4; ++p) {
      float4 a = hp[p * 128 + lane * 2];
      float4 bq = hp[p * 128 + lane * 2 + 1];
      ha0.x += a.x; ha0.y += a.y; ha0.z += a.z; ha0.w += a.w;
      ha1.x += bq.x; ha1.y += bq.y; ha1.z += bq.z; ha1.w += bq.w;
    }
    const float sc = 1.f / (float)WW;
    ha0.x *= sc; ha0.y *= sc; ha0.z *= sc; ha0.w *= sc;
    ha1.x *= sc; ha1.y *= sc; ha1.z *= sc; ha1.w *= sc;
  }

#pragma unroll 2
  for (int r = 0; r < 64; ++r) {
    const int idx = wave * 64 + r;
    const int urow = (idx < 128) ? (q * 128 + idx) : (HH + q * 128 + (idx - 128));
    const float4* up = (const float4*)(U_w + (size_t)urow * HH);
    float4 u0 = up[lane * 2], u1 = up[lane * 2 + 1];
    float s = dot4v(u0, ha0) + dot4v(u1, ha1);
    s += __shfl_xor(s, 1);
    s += __shfl_xor(s, 2);
    s += __shfl_xor(s, 4);
    s += __shfl_xor(s, 8);
    s += __shfl_xor(s, 16);
    s += __shfl_xor(s, 32);
    if (lane == 0) logitL[idx] = s;
  }
  __syncthreads();

  const int isF = (t < 128);
  const int n = q * 128 + (t & 127);
  const int row = isF ? n : (HH + n);
  const float logit = logitL[t] + gfo[(size_t)b * 2 * HH + row] + U_b[row];
  const float sg = 1.f / (1.f + __expf(-logit));

  if (isF) {
    const float* dp = denP + (size_t)b * 4 * HH + n;
    const float* np = numP + (size_t)b * 4 * HH + n;
    const float den = dp[0] + dp[HH] + dp[2 * HH] + dp[3 * HH];
    const float num = np[0] + np[HH] + np[2 * HH] + np[3 * HH];
    const float ncv = sg * c_g[(size_t)b * HH + n] + num / den;
    ncL[t] = ncv;
    out[(size_t)BB * HH + (size_t)b * HH + n] = ncv;     // new_c
  } else {
    oL[t - 128] = sg;
  }
  __syncthreads();
  if (isF) {
    out[(size_t)b * HH + n] = oL[t] * tanhf(ncL[t]);     // new_g
  }
}

extern "C" void kernel_launch(void* const* d_in, const int* in_sizes, int n_in,
                              void* d_out, int out_size, void* d_ws, size_t ws_size,
                              hipStream_t stream) {
  const float* g   = (const float*)d_in[0];
  const float* c_g = (const float*)d_in[1];
  const float* h   = (const float*)d_in[2];
  const float* c   = (const float*)d_in[3];
  const float* W_w = (const float*)d_in[4];
  const float* w_w = (const float*)d_in[5];
  const float* U_w = (const float*)d_in[6];
  const float* U_b = (const float*)d_in[7];
  const float* u_w = (const float*)d_in[8];
  const float* u_b = (const float*)d_in[9];

  float* ws    = (float*)d_ws;
  float* gw    = ws;                         // B*H
  float* gfo   = gw + BB * HH;               // B*2H
  float* hsumP = gfo + (size_t)BB * 2 * HH;  // B*4*H
  float* denP  = hsumP + (size_t)BB * 4 * HH;
  float* numP  = denP + (size_t)BB * 4 * HH;
  unsigned short* u_wb = (unsigned short*)(numP + (size_t)BB * 4 * HH);  // 512 KB
  unsigned short* hb = u_wb + 262144;        // 64 MB bf16 h image
  float* out = (float*)d_out;

  const size_t need = ((size_t)((float*)hb - ws)) * 4 + (size_t)BB * WW * HH * 2;
  const int primary = (ws_size >= need) ? 1 : 0;

  hipLaunchKernelGGL(k0, dim3(primary ? 588 : 204), dim3(256), 0, stream,
                     g, W_w, w_w, u_w, h, gw, gfo, u_wb, hb, hsumP, primary);
  if (primary) {
    hipLaunchKernelGGL(k2p, dim3(1024), dim3(512), 0, stream,
                       hb, c, u_wb, u_b, gw, denP, numP);
  } else {
    hipLaunchKernelGGL(k2f, dim3(1024), dim3(512), 0, stream,
                       h, c, u_wb, u_b, gw, denP, numP);
  }
  hipLaunchKernelGGL(k3_final, dim3(512), dim3(256), 0, stream,
                     c_g, U_w, U_b, gfo, hsumP, denP, numP, out);
}

// Round 5
// 389.340 us; speedup vs baseline: 1.0153x; 1.0153x over previous
//
#include <hip/hip_runtime.h>
#include <stdint.h>

#define BB 128
#define WW 512
#define HH 512
#define TILE 128
#define BK 64

typedef __attribute__((ext_vector_type(8))) short bf16x8;
typedef __attribute__((ext_vector_type(4))) float f32x4;

__device__ __forceinline__ float bf2f(unsigned short u) {
  union { unsigned int i; float f; } v;
  v.i = ((unsigned int)u) << 16;
  return v.f;
}
// pack two f32 into two bf16 (bit-truncation; |rel err| <= 2^-8, fine vs 6.1e-2 thr)
__device__ __forceinline__ unsigned int pack_bf2(float lo, float hi) {
  union { float f; unsigned int u; } a, b;
  a.f = lo; b.f = hi;
  return (a.u >> 16) | (b.u & 0xFFFF0000u);
}
__device__ __forceinline__ float dot4v(float4 u, float4 v) {
  return u.x * v.x + u.y * v.y + u.z * v.z + u.w * v.w;
}
__device__ __forceinline__ void gload_lds16(const void* src, void* lds_dst) {
  __builtin_amdgcn_global_load_lds(
      (const __attribute__((address_space(1))) unsigned int*)src,
      (__attribute__((address_space(3))) unsigned int*)lds_dst, 16, 0, 0);
}

// ============ K0: wide prep kernel ============
// blocks 0..11   : [gw | gfo] = g @ [w_w ; W_w].T  (MFMA GEMM, verified)
// blocks 12..75  : u_w -> pre-swizzled bf16 image u_wb (16 tiles of 256x64)
// primary mode, blocks 76..587: h -> pre-swizzled bf16 image hb (per (b,wc):
//     8 kt-tiles of 128x64, row-swizzled e^((row&7)<<3)) + column sums -> hsumP
//     [coalesced: lane owns cols 8l..8l+7; colsum in f32 regs; no in-loop barriers]
// fallback mode, blocks 76..203: column sums of h only (f32) -> hsumP partial 0
__global__ __launch_bounds__(256) void k0(
    const float* __restrict__ g, const float* __restrict__ W_w,
    const float* __restrict__ w_w, const float* __restrict__ u_w,
    const float* __restrict__ h,
    float* __restrict__ gw, float* __restrict__ gfo,
    unsigned short* __restrict__ u_wb, unsigned short* __restrict__ hb,
    float* __restrict__ hsumP, int primary) {
  __shared__ __align__(16) unsigned short As[TILE * BK];
  __shared__ __align__(16) unsigned short Bs[TILE * BK];
  const int bid = blockIdx.x;
  const int t = threadIdx.x;

  if (bid >= 76) {
    if (primary) {
      // ---- h convert + colsum: id = b*4+wc, tile = 128 rows x 512 cols.
      const int id = bid - 76;                      // 0..511
      const float* hsrc = h + (size_t)id * TILE * HH;
      unsigned short* hdst = hb + (size_t)id * (8 * 8192);
      const int lane = t & 63, wave = t >> 6;
      const int kt = lane >> 3;                     // dest tile 0..7
      const int eg = (lane & 7) * 8;                // dest col group 0..56
      float cs[8] = {0.f, 0.f, 0.f, 0.f, 0.f, 0.f, 0.f, 0.f};
      for (int r = 0; r < 32; ++r) {
        const int row = wave * 32 + r;
        const float4* sp = (const float4*)(hsrc + (size_t)row * HH + lane * 8);
        float4 u0 = sp[0], u1 = sp[1];
        uint4 pv;
        pv.x = pack_bf2(u0.x, u0.y); pv.y = pack_bf2(u0.z, u0.w);
        pv.z = pack_bf2(u1.x, u1.y); pv.w = pack_bf2(u1.z, u1.w);
        const int off = row * 64 + (eg ^ ((row & 7) << 3));
        *(uint4*)(hdst + (size_t)kt * 8192 + off) = pv;
        cs[0] += u0.x; cs[1] += u0.y; cs[2] += u0.z; cs[3] += u0.w;
        cs[4] += u1.x; cs[5] += u1.y; cs[6] += u1.z; cs[7] += u1.w;
      }
      // cross-wave colsum reduce (LDS aliased over As/Bs: 4*512 f32 = 8 KB)
      float* csh = (float*)As;
      *(float4*)(csh + wave * 512 + lane * 8)     = make_float4(cs[0], cs[1], cs[2], cs[3]);
      *(float4*)(csh + wave * 512 + lane * 8 + 4) = make_float4(cs[4], cs[5], cs[6], cs[7]);
      __syncthreads();
      for (int cc = t; cc < 512; cc += 256) {
        hsumP[(size_t)id * HH + cc] =
            csh[cc] + csh[512 + cc] + csh[1024 + cc] + csh[1536 + cc];
      }
      return;
    } else {
      // ---- fallback: colsum only, id = b (0..127); partials 1..3 zeroed
      const int b = bid - 76;
      const float* hp = h + (size_t)b * WW * HH;
      const int col0 = t * 2;
      float s0 = 0.f, s1 = 0.f;
      for (int w = 0; w < WW; ++w) {
        const float2 v = *(const float2*)(hp + (size_t)w * HH + col0);
        s0 += v.x; s1 += v.y;
      }
      hsumP[(size_t)b * 4 * HH + col0] = s0;
      hsumP[(size_t)b * 4 * HH + col0 + 1] = s1;
#pragma unroll
      for (int p = 1; p < 4; ++p) {
        hsumP[((size_t)b * 4 + p) * HH + col0] = 0.f;
        hsumP[((size_t)b * 4 + p) * HH + col0 + 1] = 0.f;
      }
      return;
    }
  }

  if (bid >= 12) {
    // ---- u_w convert: 32768 16B-chunks, 2 per thread over 64 blocks
    const int cid0 = (bid - 12) * 256 + t;
    for (int idx = cid0; idx < 32768; idx += 16384) {
      const int tile = idx >> 11;        // 2048 chunks per 32KB tile
      const int rem  = idx & 2047;
      const int row  = rem >> 3;         // 0..255
      const int eg   = (rem & 7) * 8;    // 0,8,..,56
      const int nh   = tile >> 3;
      const int kt   = tile & 7;
      const int c0   = kt * 64 + (eg ^ ((row & 7) << 3));
      const float4* sp = (const float4*)(u_w + (size_t)(nh * 256 + row) * HH + c0);
      float4 s0 = sp[0], s1 = sp[1];
      uint4 pv;
      pv.x = pack_bf2(s0.x, s0.y); pv.y = pack_bf2(s0.z, s0.w);
      pv.z = pack_bf2(s1.x, s1.y); pv.w = pack_bf2(s1.z, s1.w);
      *(uint4*)(u_wb + (size_t)idx * 8) = pv;
    }
    return;
  }

  // ---- k1 MFMA GEMM (verified)
  const int nc = bid;
  const int lane = t & 63, wave = t >> 6;
  const int wm = wave >> 1, wn = wave & 1;
  const int l15 = lane & 15, quad = lane >> 4;

  const float* wsrc = (nc < 4) ? (w_w + (size_t)nc * TILE * HH)
                               : (W_w + (size_t)(nc - 4) * TILE * HH);

  const f32x4 zero = {0.f, 0.f, 0.f, 0.f};
  f32x4 acc[4][4];
#pragma unroll
  for (int i = 0; i < 4; ++i)
#pragma unroll
    for (int j = 0; j < 4; ++j) acc[i][j] = zero;

  const int srow = t >> 3;
  const int scol = (t & 7) * 8;

  for (int kt = 0; kt < 8; ++kt) {
    const int k0i = kt * BK;
#pragma unroll
    for (int p = 0; p < 4; ++p) {
      const int row = p * 32 + srow;
      const float4* ap = (const float4*)(g    + (size_t)row * HH + k0i + scol);
      const float4* bp = (const float4*)(wsrc + (size_t)row * HH + k0i + scol);
      float4 a0 = ap[0], a1 = ap[1], b0 = bp[0], b1 = bp[1];
      uint4 av, bv;
      av.x = pack_bf2(a0.x, a0.y); av.y = pack_bf2(a0.z, a0.w);
      av.z = pack_bf2(a1.x, a1.y); av.w = pack_bf2(a1.z, a1.w);
      bv.x = pack_bf2(b0.x, b0.y); bv.y = pack_bf2(b0.z, b0.w);
      bv.z = pack_bf2(b1.x, b1.y); bv.w = pack_bf2(b1.z, b1.w);
      *(uint4*)(As + row * BK + scol) = av;
      *(uint4*)(Bs + row * BK + scol) = bv;
    }
    __syncthreads();
#pragma unroll
    for (int ks = 0; ks < 2; ++ks) {
      bf16x8 af[4], bg[4];
#pragma unroll
      for (int i = 0; i < 4; ++i)
        af[i] = *(const bf16x8*)(As + (wm * 64 + i * 16 + l15) * BK + ks * 32 + quad * 8);
#pragma unroll
      for (int j = 0; j < 4; ++j)
        bg[j] = *(const bf16x8*)(Bs + (wn * 64 + j * 16 + l15) * BK + ks * 32 + quad * 8);
#pragma unroll
      for (int i = 0; i < 4; ++i)
#pragma unroll
        for (int j = 0; j < 4; ++j)
          acc[i][j] = __builtin_amdgcn_mfma_f32_16x16x32_bf16(af[i], bg[j], acc[i][j], 0, 0, 0);
    }
    __syncthreads();
  }

#pragma unroll
  for (int j = 0; j < 4; ++j) {
    const int nl = wn * 64 + j * 16 + l15;
#pragma unroll
    for (int i = 0; i < 4; ++i) {
#pragma unroll
      for (int r = 0; r < 4; ++r) {
        const int b = wm * 64 + i * 16 + quad * 4 + r;
        const float v = acc[i][j][r];
        if (nc < 4) gw[(size_t)b * HH + nc * TILE + nl] = v;
        else        gfo[(size_t)b * 2 * HH + (nc - 4) * TILE + nl] = v;
      }
    }
  }
}

// ============ K2 primary: pure gload_lds GEMM + fused epilogue ============
// grid 1024 = (b, wc, nh). Block 128x256, 512 thr (8 waves 2Mx4N, 64x64 tiles).
// A from hb image, B from u_wb image — both pre-swizzled, loop has ~zero VALU.
__global__ __launch_bounds__(512, 4) void k2p(
    const unsigned short* __restrict__ hb, const float* __restrict__ c,
    const unsigned short* __restrict__ u_wb, const float* __restrict__ u_b,
    const float* __restrict__ gw,
    float* __restrict__ denP, float* __restrict__ numP) {
  __shared__ __align__(16) unsigned short Bs[256 * 64];   // 32 KB
  __shared__ __align__(16) unsigned short As[128 * 64];   // 16 KB
  // epilogue red-buffers aliased over As (free after final barrier)
  float (*redD)[256] = (float (*)[256])(void*)As;
  float (*redN)[256] = (float (*)[256])(void*)(As + 1024);

  const int bid = blockIdx.x;
  const int b  = bid >> 3;
  const int wc = (bid >> 1) & 3;
  const int nh = bid & 1;
  const int t = threadIdx.x;
  const int lane = t & 63, wave = t >> 6;
  const int wm = wave >> 2, wn = wave & 3;
  const int l15 = lane & 15, quad = lane >> 4;

  const size_t hbase = ((size_t)b * WW + (size_t)wc * 128) * HH;
  const unsigned short* hbA = hb + (size_t)(bid >> 1) * (8 * 8192);
  const unsigned short* ubase = u_wb + (size_t)nh * 8 * 16384;

  const f32x4 zero = {0.f, 0.f, 0.f, 0.f};
  f32x4 acc[4][4];
#pragma unroll
  for (int i = 0; i < 4; ++i)
#pragma unroll
    for (int j = 0; j < 4; ++j) acc[i][j] = zero;

  for (int kt = 0; kt < 8; ++kt) {
    // A: 16 KB = 16 segs of 1 KB; wave handles segs wave*2, wave*2+1
#pragma unroll
    for (int it = 0; it < 2; ++it) {
      const int s = wave * 2 + it;
      gload_lds16(hbA + (size_t)kt * 8192 + (size_t)s * 512 + (size_t)lane * 8,
                  As + (size_t)s * 512);
    }
    // B: 32 KB = 32 segs; wave handles segs wave*4 .. +3
#pragma unroll
    for (int it = 0; it < 4; ++it) {
      const int s = wave * 4 + it;
      gload_lds16(ubase + (size_t)kt * 16384 + (size_t)s * 512 + (size_t)lane * 8,
                  Bs + (size_t)s * 512);
    }
    __syncthreads();

#pragma unroll
    for (int ks = 0; ks < 2; ++ks) {
      bf16x8 af[4], bg[4];
#pragma unroll
      for (int i = 0; i < 4; ++i) {
        const int row = wm * 64 + i * 16 + l15;
        af[i] = *(const bf16x8*)(As + row * 64 + ((ks * 32 + quad * 8) ^ ((row & 7) << 3)));
      }
#pragma unroll
      for (int j = 0; j < 4; ++j) {
        const int row = wn * 64 + j * 16 + l15;
        bg[j] = *(const bf16x8*)(Bs + row * 64 + ((ks * 32 + quad * 8) ^ ((row & 7) << 3)));
      }
#pragma unroll
      for (int i = 0; i < 4; ++i)
#pragma unroll
        for (int j = 0; j < 4; ++j)
          acc[i][j] = __builtin_amdgcn_mfma_f32_16x16x32_bf16(af[i], bg[j], acc[i][j], 0, 0, 0);
    }
    __syncthreads();
  }

  // Epilogue: e = exp(sigmoid(Z + gw + u_b)); reduce over this block's 128 w's.
  const int N0 = nh * 256;
#pragma unroll
  for (int j = 0; j < 4; ++j) {
    const int n = wn * 64 + j * 16 + l15;
    const float gwub = gw[(size_t)b * HH + N0 + n] + u_b[N0 + n];
    float dsum = 0.f, nsum = 0.f;
#pragma unroll
    for (int i = 0; i < 4; ++i) {
#pragma unroll
      for (int r = 0; r < 4; ++r) {
        const int m = wm * 64 + i * 16 + quad * 4 + r;
        const float z = acc[i][j][r] + gwub;
        const float sig = 1.f / (1.f + __expf(-z));
        const float e = __expf(sig);
        dsum += e;
        nsum += e * c[hbase + (size_t)m * HH + N0 + n];
      }
    }
    dsum += __shfl_xor(dsum, 16);
    dsum += __shfl_xor(dsum, 32);
    nsum += __shfl_xor(nsum, 16);
    nsum += __shfl_xor(nsum, 32);
    if (quad == 0) { redD[wm][n] = dsum; redN[wm][n] = nsum; }
  }
  __syncthreads();
  if (t < 256) {
    const size_t o = ((size_t)b * 4 + wc) * HH + N0 + t;
    denP[o] = redD[0][t] + redD[1][t];
    numP[o] = redN[0][t] + redN[1][t];
  }
}

// ============ K2 fallback: round-2 structure (f32 h staging), no colsum ============
__global__ __launch_bounds__(512, 4) void k2f(
    const float* __restrict__ h, const float* __restrict__ c,
    const unsigned short* __restrict__ u_wb, const float* __restrict__ u_b,
    const float* __restrict__ gw,
    float* __restrict__ denP, float* __restrict__ numP) {
  __shared__ __align__(16) unsigned short Bs[256 * 64];
  __shared__ __align__(16) unsigned short As[128 * 64];
  float (*redD)[256] = (float (*)[256])(void*)As;
  float (*redN)[256] = (float (*)[256])(void*)(As + 1024);

  const int bid = blockIdx.x;
  const int b  = bid >> 3;
  const int wc = (bid >> 1) & 3;
  const int nh = bid & 1;
  const int t = threadIdx.x;
  const int lane = t & 63, wave = t >> 6;
  const int wm = wave >> 2, wn = wave & 3;
  const int l15 = lane & 15, quad = lane >> 4;

  const size_t hbase = ((size_t)b * WW + (size_t)wc * 128) * HH;
  const unsigned short* ubase = u_wb + (size_t)nh * 8 * 16384;

  const f32x4 zero = {0.f, 0.f, 0.f, 0.f};
  f32x4 acc[4][4];
#pragma unroll
  for (int i = 0; i < 4; ++i)
#pragma unroll
    for (int j = 0; j < 4; ++j) acc[i][j] = zero;

  const int srow = t >> 3;
  const int scol = (t & 7) * 8;

  for (int kt = 0; kt < 8; ++kt) {
    const int k0i = kt * 64;
#pragma unroll
    for (int it = 0; it < 4; ++it) {
      const int s = wave * 4 + it;
      gload_lds16(ubase + ((size_t)kt * 16384 + (size_t)s * 512 + (size_t)lane * 8),
                  Bs + (size_t)s * 512);
    }
#pragma unroll
    for (int p = 0; p < 2; ++p) {
      const int row = p * 64 + srow;
      const float4* ap = (const float4*)(h + hbase + (size_t)row * HH + k0i + scol);
      float4 a0 = ap[0], a1 = ap[1];
      uint4 av;
      av.x = pack_bf2(a0.x, a0.y); av.y = pack_bf2(a0.z, a0.w);
      av.z = pack_bf2(a1.x, a1.y); av.w = pack_bf2(a1.z, a1.w);
      *(uint4*)(As + row * 64 + (scol ^ ((row & 7) << 3))) = av;
    }
    __syncthreads();
#pragma unroll
    for (int ks = 0; ks < 2; ++ks) {
      bf16x8 af[4], bg[4];
#pragma unroll
      for (int i = 0; i < 4; ++i) {
        const int row = wm * 64 + i * 16 + l15;
        af[i] = *(const bf16x8*)(As + row * 64 + ((ks * 32 + quad * 8) ^ ((row & 7) << 3)));
      }
#pragma unroll
      for (int j = 0; j < 4; ++j) {
        const int row = wn * 64 + j * 16 + l15;
        bg[j] = *(const bf16x8*)(Bs + row * 64 + ((ks * 32 + quad * 8) ^ ((row & 7) << 3)));
      }
#pragma unroll
      for (int i = 0; i < 4; ++i)
#pragma unroll
        for (int j = 0; j < 4; ++j)
          acc[i][j] = __builtin_amdgcn_mfma_f32_16x16x32_bf16(af[i], bg[j], acc[i][j], 0, 0, 0);
    }
    __syncthreads();
  }

  const int N0 = nh * 256;
#pragma unroll
  for (int j = 0; j < 4; ++j) {
    const int n = wn * 64 + j * 16 + l15;
    const float gwub = gw[(size_t)b * HH + N0 + n] + u_b[N0 + n];
    float dsum = 0.f, nsum = 0.f;
#pragma unroll
    for (int i = 0; i < 4; ++i) {
#pragma unroll
      for (int r = 0; r < 4; ++r) {
        const int m = wm * 64 + i * 16 + quad * 4 + r;
        const float z = acc[i][j][r] + gwub;
        const float sig = 1.f / (1.f + __expf(-z));
        const float e = __expf(sig);
        dsum += e;
        nsum += e * c[hbase + (size_t)m * HH + N0 + n];
      }
    }
    dsum += __shfl_xor(dsum, 16);
    dsum += __shfl_xor(dsum, 32);
    nsum += __shfl_xor(nsum, 16);
    nsum += __shfl_xor(nsum, 32);
    if (quad == 0) { redD[wm][n] = dsum; redN[wm][n] = nsum; }
  }
  __syncthreads();
  if (t < 256) {
    const size_t o = ((size_t)b * 4 + wc) * HH + N0 + t;
    denP[o] = redD[0][t] + redD[1][t];
    numP[o] = redN[0][t] + redN[1][t];
  }
}

// -------- K3: fo gates + final outputs. grid 512 = (b, q); 256 thr = 4 waves.
__global__ __launch_bounds__(256) void k3_final(
    const float* __restrict__ c_g, const float* __restrict__ U_w,
    const float* __restrict__ U_b,
    const float* __restrict__ gfo, const float* __restrict__ hsumP,
    const float* __restrict__ denP, const float* __restrict__ numP,
    float* __restrict__ out) {
  __shared__ float logitL[256];
  __shared__ float ncL[128];
  __shared__ float oL[128];
  const int bid = blockIdx.x;
  const int b = bid >> 2, q = bid & 3;
  const int t = threadIdx.x;
  const int lane = t & 63, wave = t >> 6;

  // ha in registers: lane l holds k = 8l .. 8l+7
  float4 ha0 = {0.f, 0.f, 0.f, 0.f}, ha1 = {0.f, 0.f, 0.f, 0.f};
  {
    const float4* hp = (const float4*)(hsumP + (size_t)b * 4 * HH);
#pragma unroll
    for (int p = 0; p < 4; ++p) {
      float4 a = hp[p * 128 + lane * 2];
      float4 bq = hp[p * 128 + lane * 2 + 1];
      ha0.x += a.x; ha0.y += a.y; ha0.z += a.z; ha0.w += a.w;
      ha1.x += bq.x; ha1.y += bq.y; ha1.z += bq.z; ha1.w += bq.w;
    }
    const float sc = 1.f / (float)WW;
    ha0.x *= sc; ha0.y *= sc; ha0.z *= sc; ha0.w *= sc;
    ha1.x *= sc; ha1.y *= sc; ha1.z *= sc; ha1.w *= sc;
  }

#pragma unroll 2
  for (int r = 0; r < 64; ++r) {
    const int idx = wave * 64 + r;
    const int urow = (idx < 128) ? (q * 128 + idx) : (HH + q * 128 + (idx - 128));
    const float4* up = (const float4*)(U_w + (size_t)urow * HH);
    float4 u0 = up[lane * 2], u1 = up[lane * 2 + 1];
    float s = dot4v(u0, ha0) + dot4v(u1, ha1);
    s += __shfl_xor(s, 1);
    s += __shfl_xor(s, 2);
    s += __shfl_xor(s, 4);
    s += __shfl_xor(s, 8);
    s += __shfl_xor(s, 16);
    s += __shfl_xor(s, 32);
    if (lane == 0) logitL[idx] = s;
  }
  __syncthreads();

  const int isF = (t < 128);
  const int n = q * 128 + (t & 127);
  const int row = isF ? n : (HH + n);
  const float logit = logitL[t] + gfo[(size_t)b * 2 * HH + row] + U_b[row];
  const float sg = 1.f / (1.f + __expf(-logit));

  if (isF) {
    const float* dp = denP + (size_t)b * 4 * HH + n;
    const float* np = numP + (size_t)b * 4 * HH + n;
    const float den = dp[0] + dp[HH] + dp[2 * HH] + dp[3 * HH];
    const float num = np[0] + np[HH] + np[2 * HH] + np[3 * HH];
    const float ncv = sg * c_g[(size_t)b * HH + n] + num / den;
    ncL[t] = ncv;
    out[(size_t)BB * HH + (size_t)b * HH + n] = ncv;     // new_c
  } else {
    oL[t - 128] = sg;
  }
  __syncthreads();
  if (isF) {
    out[(size_t)b * HH + n] = oL[t] * tanhf(ncL[t]);     // new_g
  }
}

extern "C" void kernel_launch(void* const* d_in, const int* in_sizes, int n_in,
                              void* d_out, int out_size, void* d_ws, size_t ws_size,
                              hipStream_t stream) {
  const float* g   = (const float*)d_in[0];
  const float* c_g = (const float*)d_in[1];
  const float* h   = (const float*)d_in[2];
  const float* c   = (const float*)d_in[3];
  const float* W_w = (const float*)d_in[4];
  const float* w_w = (const float*)d_in[5];
  const float* U_w = (const float*)d_in[6];
  const float* U_b = (const float*)d_in[7];
  const float* u_w = (const float*)d_in[8];
  const float* u_b = (const float*)d_in[9];

  float* ws    = (float*)d_ws;
  float* gw    = ws;                         // B*H
  float* gfo   = gw + BB * HH;               // B*2H
  float* hsumP = gfo + (size_t)BB * 2 * HH;  // B*4*H
  float* denP  = hsumP + (size_t)BB * 4 * HH;
  float* numP  = denP + (size_t)BB * 4 * HH;
  unsigned short* u_wb = (unsigned short*)(numP + (size_t)BB * 4 * HH);  // 512 KB
  unsigned short* hb = u_wb + 262144;        // 64 MB bf16 h image
  float* out = (float*)d_out;

  const size_t need = ((size_t)((float*)hb - ws)) * 4 + (size_t)BB * WW * HH * 2;
  const int primary = (ws_size >= need) ? 1 : 0;

  hipLaunchKernelGGL(k0, dim3(primary ? 588 : 204), dim3(256), 0, stream,
                     g, W_w, w_w, u_w, h, gw, gfo, u_wb, hb, hsumP, primary);
  if (primary) {
    hipLaunchKernelGGL(k2p, dim3(1024), dim3(512), 0, stream,
                       hb, c, u_wb, u_b, gw, denP, numP);
  } else {
    hipLaunchKernelGGL(k2f, dim3(1024), dim3(512), 0, stream,
                       h, c, u_wb, u_b, gw, denP, numP);
  }
  hipLaunchKernelGGL(k3_final, dim3(512), dim3(256), 0, stream,
                     c_g, U_w, U_b, gfo, hsumP, denP, numP, out);
}